// Round 6
// baseline (28352.808 us; speedup 1.0000x reference)
//
#include <hip/hip_runtime.h>

// Problem constants
#define B_  128
#define T_  512
#define I_  512
#define H_  1024
#define G4  4096   // 4*H

typedef __attribute__((ext_vector_type(8))) short   short8;
typedef __attribute__((ext_vector_type(4))) short   short4v;
typedef __attribute__((ext_vector_type(4))) float   f32x4;
typedef unsigned long long u64;

__device__ __forceinline__ float bf2f(short u){
  return __uint_as_float(((unsigned)(unsigned short)u) << 16);
}
__device__ __forceinline__ short f2bf(float f){
  unsigned u = __float_as_uint(f);
  unsigned r = (u + 0x7FFFu + ((u >> 16) & 1u)) >> 16;  // RNE
  return (short)r;
}
__device__ __forceinline__ float sigm(float x){ return 1.0f/(1.0f + __expf(-x)); }
__device__ __forceinline__ float tanh_(float x){ return 1.0f - 2.0f/(__expf(2.0f*x) + 1.0f); }

// ---------------- fp32 -> bf16 elementwise convert (vectorized x4) ----------------
__global__ __launch_bounds__(256) void cvt_bf16(const float* __restrict__ in,
                                                short* __restrict__ out, int nq){
  int i = blockIdx.x*256 + threadIdx.x;
  if (i >= nq) return;
  float4 v = ((const float4*)in)[i];
  short4v o; o.x = f2bf(v.x); o.y = f2bf(v.y); o.z = f2bf(v.z); o.w = f2bf(v.w);
  ((short4v*)out)[i] = o;
}

// ---------------- W_hh fp32 [4096][1024] -> bf16 MFMA-fragment-swizzled ----------------
// out chunk index c = ((g*64 + jf)*32 + s)*64 + l ; chunk = 8 bf16 (16B)
// represents W[g*1024 + jf*16 + (l&15)][s*32 + (l>>4)*8 + e]
__global__ __launch_bounds__(256) void swz_whh(const float* __restrict__ W,
                                               short* __restrict__ out){
  int c = blockIdx.x*256 + threadIdx.x;      // 0 .. 524287
  int l = c & 63, s = (c >> 6) & 31, jf = (c >> 11) & 63, g = c >> 17;
  long row = (long)(g*1024 + jf*16 + (l & 15));
  int col = s*32 + (l >> 4)*8;
  const float* src = W + row*H_ + col;
  short8 o;
#pragma unroll
  for (int e = 0; e < 8; ++e) o[e] = f2bf(src[e]);
  ((short8*)out)[c] = o;
}

// ---------------- projection GEMM: C[m,n] = sum_k A[m,k]*W[n,k] + bih[n]+bhh[n] ----------------
// Output written in scan-swizzled xg layout:
//   idx = ((((t*8 + bt)*64 + jf)*4 + g)*256 + bl*16 + jl
template<int K>
__global__ __launch_bounds__(256) void proj_gemm(const short* __restrict__ A,
                                                 const short* __restrict__ W,
                                                 const float* __restrict__ bih,
                                                 const float* __restrict__ bhh,
                                                 short* __restrict__ C){
  __shared__ short lds[2][2][128*40];  // [buf][A/B][row*40+col], pad 40 kills conflicts
  const int tid = threadIdx.x;
  const int l  = tid & 63, wv = tid >> 6;
  const int wm = wv >> 1,  wn = wv & 1;
  const int nt = blockIdx.x, mt = blockIdx.y;
  const int r0 = tid >> 2, cb = (tid & 3) * 8;
  const short* Ab = A + (long)(mt*128 + r0)*K + cb;
  const short* Wb = W + (long)(nt*128 + r0)*K + cb;
  const int lo  = r0*40 + cb;
  const int lo2 = lo + 64*40;
  const int NK = K/32;

  short8 pa0 = *(const short8*)(Ab);
  short8 pa1 = *(const short8*)(Ab + 64*K);
  short8 pb0 = *(const short8*)(Wb);
  short8 pb1 = *(const short8*)(Wb + 64*K);
  *(short8*)&lds[0][0][lo]  = pa0;
  *(short8*)&lds[0][0][lo2] = pa1;
  *(short8*)&lds[0][1][lo]  = pb0;
  *(short8*)&lds[0][1][lo2] = pb1;

  f32x4 acc[4][4];
  f32x4 z = {0.f,0.f,0.f,0.f};
#pragma unroll
  for (int i = 0; i < 4; ++i)
#pragma unroll
    for (int j = 0; j < 4; ++j) acc[i][j] = z;

  for (int kt = 0; kt < NK; ++kt){
    __syncthreads();
    if (kt + 1 < NK){
      pa0 = *(const short8*)(Ab + (kt+1)*32);
      pa1 = *(const short8*)(Ab + (kt+1)*32 + 64*K);
      pb0 = *(const short8*)(Wb + (kt+1)*32);
      pb1 = *(const short8*)(Wb + (kt+1)*32 + 64*K);
    }
    const short* As = lds[kt & 1][0];
    const short* Bs = lds[kt & 1][1];
    short8 bfr[4];
#pragma unroll
    for (int nf = 0; nf < 4; ++nf)
      bfr[nf] = *(const short8*)&Bs[(wn*64 + nf*16 + (l & 15))*40 + (l >> 4)*8];
#pragma unroll
    for (int mf = 0; mf < 4; ++mf){
      short8 af = *(const short8*)&As[(wm*64 + mf*16 + (l & 15))*40 + (l >> 4)*8];
#pragma unroll
      for (int nf = 0; nf < 4; ++nf)
        acc[mf][nf] = __builtin_amdgcn_mfma_f32_16x16x32_bf16(af, bfr[nf], acc[mf][nf], 0, 0, 0);
    }
    if (kt + 1 < NK){
      int nb = (kt + 1) & 1;
      *(short8*)&lds[nb][0][lo]  = pa0;
      *(short8*)&lds[nb][0][lo2] = pa1;
      *(short8*)&lds[nb][1][lo]  = pb0;
      *(short8*)&lds[nb][1][lo2] = pb1;
    }
  }

  const int mrow0 = mt*128 + wm*64;
  const int ncol0 = nt*128 + wn*64;
#pragma unroll
  for (int nf = 0; nf < 4; ++nf){
    int n = ncol0 + nf*16 + (l & 15);      // n = g*1024 + jf*16 + jl
    int g  = n >> 10;
    int jfn = (n >> 4) & 63;
    int jl  = n & 15;
    float bs = bih[n] + bhh[n];
#pragma unroll
    for (int mf = 0; mf < 4; ++mf){
#pragma unroll
      for (int r = 0; r < 4; ++r){
        int m = mrow0 + mf*16 + (l >> 4)*4 + r;   // C/D: row=(l>>4)*4+r, col=l&15
        int b = m >> 9, t = m & 511;
        long idx = ((((long)t*8 + (b >> 4))*64 + jfn)*4 + g)*256 + (b & 15)*16 + jl;
        C[idx] = f2bf(acc[mf][nf][r] + bs);
      }
    }
  }
}

// ---------------- persistent LSTM scan (one launch per layer) ----------------
// grid (bt=8, jf=64) = 512 blocks x 256 thr; 2 blocks/CU.
// W_hh slice register-resident (asm-pinned). Per step:
//   gather h (PLAIN dwordx4 via L2; fresh because of prior acquire-fence inv)
//   -> 32 MFMA/wave -> LDS reduce -> EW
//   -> wave-local pack (own 8 chunks only; no cross-wave LDS read)
//   -> 8x dwordx4 sc1 (write-through, device-visible) -> vmcnt(0)
//   -> one atomic counter add per wave -> out stores (sc1, never dirty)
//   -> xg prefetch -> 1-lane poll of quarter counter ==64 -> acquire fence.
// No placement assumptions; all cross-block data flows through device-scope
// stores + acquire fences (G16-safe).
//
// h layout: region (bt,wv) = 8KB; chunk c (16B) = h[bt*16 + (c&15)]
//   [wv*256 + (c>>6)*32 + ((c>>4)&3)*8 + e]. Consumer wave wv: a[ks] =
//   chunk[ks*64 + l]. Producer wave wv of block jf owns 8 full chunks.
template<int LAYER>
__global__ __launch_bounds__(256, 2) void lstm_scan(
    short* __restrict__ hb0, short* __restrict__ hb1,
    const short* __restrict__ Wsw, const short* __restrict__ xg,
    const float* __restrict__ om, const float* __restrict__ hm, const float* __restrict__ cm,
    short* __restrict__ out0, float* __restrict__ dout,
    int* __restrict__ cnt)       // [8 bt][512 t][4 quarter] counters, pre-zeroed
{
  const int tid = threadIdx.x;
  const int l = tid & 63, wv = tid >> 6;
  const int bt = blockIdx.x, jf = blockIdx.y;

  // ---- load W fragments once; pin in registers ----
  short8 w[4][8];
#pragma unroll
  for (int g = 0; g < 4; ++g){
    const short8* wp = (const short8*)Wsw + ((g*64 + jf)*32 + wv*8)*64 + l;
#pragma unroll
    for (int ks = 0; ks < 8; ++ks) w[g][ks] = wp[ks*64];
  }
  {
    f32x4* wf = (f32x4*)w;
#pragma unroll
    for (int i = 0; i < 32; ++i) asm volatile("" : "+v"(wf[i]));
  }

  // ---- elementwise-role constants ----
  const int bl = tid >> 4, jl = tid & 15;
  const int jcol = jf*16 + jl;
  const long bj = (long)(bt*16 + bl)*H_ + jcol;
  const float mo = om[bj], mh = hm[bj], mc = cm[bj];
  float c = 0.f;
  const int lsrc = ((bl >> 2) << 4) | jl;   // lane holding acc row bl, col jl
  const int rr = bl & 3;

  // consumer gather base (bytes): region (bt,wv) + lane chunk
  const long cbyte = (long)(bt*4 + wv)*8192 + l*16;
  // producer: wave wv of block jf stores 8 chunks; lane p<8: jh=p>>2, blq=p&3
  //   chunk = ((jf>>1)&7)*64 + ((jf&1)*2 + jh)*16 + wv*4 + blq
  const long pbyte = (long)(bt*4 + (jf >> 4))*8192
                   + (long)(((jf >> 1) & 7)*64 + ((jf & 1)*2 + (l >> 2))*16 + wv*4 + (l & 3))*16;
  // sstage pack slot: wave region wv*64, chunk (jl>>3)*4 + (bl&3), elem jl&7
  const int sidx = wv*64 + ((jl >> 3)*4 + (bl & 3))*8 + (jl & 7);

  __shared__ float red[16*264];             // padded: kills 4-way reduce-read conflict
  __shared__ __align__(16) short sstage[256];
  int* fl4 = cnt + (long)bt*T_*4;

  // xg prefetch for t=0
  const short* xg0 = xg + (((long)bt)*64 + jf)*1024;
  short xv0 = xg0[tid], xv1 = xg0[256 + tid], xv2 = xg0[512 + tid], xv3 = xg0[768 + tid];

  for (int t = 0; t < T_; ++t){
    // ---- gather h slice: plain dwordx4 through L2 (fresh: fence at loop end) ----
    const char* hsrc = (const char*)(t & 1 ? hb1 : hb0) + cbyte;
    short8 a[8];
#pragma unroll
    for (int ks = 0; ks < 8; ++ks)
      a[ks] = *(const short8*)(hsrc + ks*1024);

    f32x4 acc[4];
    f32x4 z = {0.f,0.f,0.f,0.f};
#pragma unroll
    for (int g = 0; g < 4; ++g) acc[g] = z;
#pragma unroll
    for (int g = 0; g < 4; ++g)
#pragma unroll
      for (int ks = 0; ks < 8; ++ks)
        acc[g] = __builtin_amdgcn_mfma_f32_16x16x32_bf16(a[ks], w[g][ks], acc[g], 0, 0, 0);

#pragma unroll
    for (int g = 0; g < 4; ++g)
#pragma unroll
      for (int r = 0; r < 4; ++r)
        red[(g*4 + r)*264 + tid] = acc[g][r];
    __syncthreads();

    // ---- elementwise (thread owns (bl, jl)) ----
    float gate[4];
    short xvv[4] = {xv0, xv1, xv2, xv3};
#pragma unroll
    for (int g = 0; g < 4; ++g){
      const float* rrow = &red[(g*4 + rr)*264];
      float s = rrow[lsrc] + rrow[64 + lsrc] + rrow[128 + lsrc] + rrow[192 + lsrc];
      gate[g] = s + bf2f(xvv[g]);
    }
    float ii = sigm(gate[0]);
    float ff = sigm(gate[1]);
    float gg = tanh_(gate[2]);
    float oo = sigm(gate[3]);
    float c2 = ff*c + ii*gg;
    float h2 = oo*tanh_(c2);
    c = c2*mc;
    float hn = h2*mh;

    if (t < T_ - 1){
      // ---- wave-local pack: each wave writes & reads ONLY its own 128B ----
      sstage[sidx] = f2bf(hn);
      asm volatile("s_waitcnt lgkmcnt(0)" ::: "memory");   // own wave's ds_write done
      __builtin_amdgcn_sched_barrier(0);
      if (l < 8){
        short8 pk = ((const short8*)sstage)[wv*8 + l];
        char* hdst = (char*)(t & 1 ? hb0 : hb1) + pbyte;
        asm volatile("global_store_dwordx4 %0, %1, off sc1" :: "v"(hdst), "v"(pk) : "memory");
      }
      asm volatile("s_waitcnt vmcnt(0)" ::: "memory");     // h device-visible
      if (l == 0)
        __hip_atomic_fetch_add(&fl4[t*4 + (jf >> 4)], 1, __ATOMIC_RELAXED, __HIP_MEMORY_SCOPE_AGENT);
    }

    // ---- out stores: write-through sc1 (no dirty L2 lines, overlap poll) ----
    if (LAYER == 0){
      short* op = out0 + ((long)(bt*16 + bl)*T_ + t)*H_ + jcol;
      int ov = (unsigned short)f2bf(h2*mo);
      asm volatile("global_store_short %0, %1, off sc1" :: "v"(op), "v"(ov) : "memory");
    } else {
      float* dp = dout + ((long)(bt*16 + bl)*T_ + t)*H_ + jcol;
      float ov = h2*mo;
      asm volatile("global_store_dword %0, %1, off sc1" :: "v"(dp), "v"(ov) : "memory");
      if (t == T_ - 1){
        float* hp_ = dout + (long)B_*T_*H_ + bj;
        float* cp_ = dout + (long)B_*T_*H_ + (long)B_*H_ + bj;
        asm volatile("global_store_dword %0, %1, off sc1" :: "v"(hp_), "v"(hn) : "memory");
        asm volatile("global_store_dword %0, %1, off sc1" :: "v"(cp_), "v"(c)  : "memory");
      }
    }

    if (t == T_ - 1) break;

    // ---- xg prefetch for t+1 (overlaps poll) ----
    const short* xgn = xg + (((long)(t+1)*8 + bt)*64 + jf)*1024;
    xv0 = xgn[tid]; xv1 = xgn[256 + tid]; xv2 = xgn[512 + tid]; xv3 = xgn[768 + tid];

    // ---- 1-lane-per-wave poll: quarter wv complete when counter == 64 ----
    if (l == 0){
      int g = 0;
      while (__hip_atomic_load(&fl4[t*4 + wv], __ATOMIC_RELAXED, __HIP_MEMORY_SCOPE_AGENT) != 64){
        if (++g > (1 << 20)) break;   // safety: wrong-answer instead of hang
      }
    }
    // invalidate stale L0/L2 so next gather reads fresh h (W is in registers;
    // nothing valuable is cached -> inv is cheap)
    __builtin_amdgcn_fence(__ATOMIC_ACQUIRE, "agent");
  }
}

extern "C" void kernel_launch(void* const* d_in, const int* in_sizes, int n_in,
                              void* d_out, int out_size, void* d_ws, size_t ws_size,
                              hipStream_t stream){
  const float* x    = (const float*)d_in[0];
  const float* Wih0 = (const float*)d_in[1];
  const float* Whh0 = (const float*)d_in[2];
  const float* bih0 = (const float*)d_in[3];
  const float* bhh0 = (const float*)d_in[4];
  const float* Wih1 = (const float*)d_in[5];
  const float* Whh1 = (const float*)d_in[6];
  const float* bih1 = (const float*)d_in[7];
  const float* bhh1 = (const float*)d_in[8];
  const float* omsk = (const float*)d_in[9];
  const float* hmsk = (const float*)d_in[10];
  const float* cmsk = (const float*)d_in[11];
  float* out = (float*)d_out;

  char* p = (char*)d_ws;
  auto alloc = [&](size_t bytes)->char*{
    char* r = p; p += (bytes + 255) & ~(size_t)255; return r;
  };
  short* xg      = (short*)alloc((size_t)65536*4096*2);   // swizzled xg (shared by both layers)
  short* x_bf    = (short*)alloc((size_t)33554432*2);     // x as bf16, [b*T+t][512]
  short* out0_bf = (short*)alloc((size_t)67108864*2);     // layer-0 outputs, bf16
  short* wih0_bf = (short*)alloc((size_t)2097152*2);
  short* wih1_bf = (short*)alloc((size_t)4194304*2);
  short* whh0_sw = (short*)alloc((size_t)4194304*2);
  short* whh1_sw = (short*)alloc((size_t)4194304*2);
  short* hb0     = (short*)alloc((size_t)131072*2);
  short* hb1     = (short*)alloc((size_t)131072*2);
  int*   cnt0    = (int*)alloc((size_t)8*512*4*4);        // 64 KB counters
  int*   cnt1    = (int*)alloc((size_t)8*512*4*4);
  if ((size_t)(p - (char*)d_ws) > ws_size) return;   // workspace too small — bail

  // counters must be zero at scan start (deterministic across graph replays)
  hipMemsetAsync(cnt0, 0, (size_t)8*512*4*4, stream);
  hipMemsetAsync(cnt1, 0, (size_t)8*512*4*4, stream);

  // converts / weight swizzles
  cvt_bf16<<<33554432/4/256, 256, 0, stream>>>(x,    x_bf,    33554432/4);
  cvt_bf16<<<2097152/4/256,  256, 0, stream>>>(Wih0, wih0_bf, 2097152/4);
  cvt_bf16<<<4194304/4/256,  256, 0, stream>>>(Wih1, wih1_bf, 4194304/4);
  swz_whh <<<524288/256,     256, 0, stream>>>(Whh0, whh0_sw);
  swz_whh <<<524288/256,     256, 0, stream>>>(Whh1, whh1_sw);

  // ---- layer 0 ----
  proj_gemm<512><<<dim3(32, 512), 256, 0, stream>>>(x_bf, wih0_bf, bih0, bhh0, xg);
  hipMemsetAsync(hb0, 0, 262144, stream);
  lstm_scan<0><<<dim3(8, 64), 256, 0, stream>>>(hb0, hb1, whh0_sw, xg,
      omsk, hmsk, cmsk, out0_bf, nullptr, cnt0);

  // ---- layer 1 ----
  proj_gemm<1024><<<dim3(32, 512), 256, 0, stream>>>(out0_bf, wih1_bf, bih1, bhh1, xg);
  hipMemsetAsync(hb0, 0, 262144, stream);
  lstm_scan<1><<<dim3(8, 64), 256, 0, stream>>>(hb0, hb1, whh1_sw, xg,
      omsk + 131072, hmsk + 131072, cmsk + 131072, nullptr, out, cnt1);
}

// Round 7
// 7405.888 us; speedup vs baseline: 3.8284x; 3.8284x over previous
//
#include <hip/hip_runtime.h>

// Problem constants
#define B_  128
#define T_  512
#define I_  512
#define H_  1024
#define G4  4096   // 4*H
#define SLOT 262144L   // 256 KB per h ring slot (B*H*2)

typedef __attribute__((ext_vector_type(8))) short   short8;
typedef __attribute__((ext_vector_type(4))) short   short4v;
typedef __attribute__((ext_vector_type(4))) float   f32x4;
typedef unsigned long long u64;

__device__ __forceinline__ float bf2f(short u){
  return __uint_as_float(((unsigned)(unsigned short)u) << 16);
}
__device__ __forceinline__ short f2bf(float f){
  unsigned u = __float_as_uint(f);
  unsigned r = (u + 0x7FFFu + ((u >> 16) & 1u)) >> 16;  // RNE
  return (short)r;
}
__device__ __forceinline__ float sigm(float x){ return 1.0f/(1.0f + __expf(-x)); }
__device__ __forceinline__ float tanh_(float x){ return 1.0f - 2.0f/(__expf(2.0f*x) + 1.0f); }

// ---------------- fp32 -> bf16 elementwise convert (vectorized x4) ----------------
__global__ __launch_bounds__(256) void cvt_bf16(const float* __restrict__ in,
                                                short* __restrict__ out, int nq){
  int i = blockIdx.x*256 + threadIdx.x;
  if (i >= nq) return;
  float4 v = ((const float4*)in)[i];
  short4v o; o.x = f2bf(v.x); o.y = f2bf(v.y); o.z = f2bf(v.z); o.w = f2bf(v.w);
  ((short4v*)out)[i] = o;
}

// ---------------- W_hh fp32 [4096][1024] -> bf16 MFMA-fragment-swizzled ----------------
// out chunk index c = ((g*64 + jf)*32 + s)*64 + l ; chunk = 8 bf16 (16B)
// represents W[g*1024 + jf*16 + (l&15)][s*32 + (l>>4)*8 + e]
__global__ __launch_bounds__(256) void swz_whh(const float* __restrict__ W,
                                               short* __restrict__ out){
  int c = blockIdx.x*256 + threadIdx.x;      // 0 .. 524287
  int l = c & 63, s = (c >> 6) & 31, jf = (c >> 11) & 63, g = c >> 17;
  long row = (long)(g*1024 + jf*16 + (l & 15));
  int col = s*32 + (l >> 4)*8;
  const float* src = W + row*H_ + col;
  short8 o;
#pragma unroll
  for (int e = 0; e < 8; ++e) o[e] = f2bf(src[e]);
  ((short8*)out)[c] = o;
}

// ---------------- projection GEMM: C[m,n] = sum_k A[m,k]*W[n,k] + bih[n]+bhh[n] ----------------
// Output written in scan-swizzled xg layout:
//   idx = ((((t*8 + bt)*64 + jf)*4 + g)*256 + bl*16 + jl
template<int K>
__global__ __launch_bounds__(256) void proj_gemm(const short* __restrict__ A,
                                                 const short* __restrict__ W,
                                                 const float* __restrict__ bih,
                                                 const float* __restrict__ bhh,
                                                 short* __restrict__ C){
  __shared__ short lds[2][2][128*40];  // [buf][A/B][row*40+col], pad 40 kills conflicts
  const int tid = threadIdx.x;
  const int l  = tid & 63, wv = tid >> 6;
  const int wm = wv >> 1,  wn = wv & 1;
  const int nt = blockIdx.x, mt = blockIdx.y;
  const int r0 = tid >> 2, cb = (tid & 3) * 8;
  const short* Ab = A + (long)(mt*128 + r0)*K + cb;
  const short* Wb = W + (long)(nt*128 + r0)*K + cb;
  const int lo  = r0*40 + cb;
  const int lo2 = lo + 64*40;
  const int NK = K/32;

  short8 pa0 = *(const short8*)(Ab);
  short8 pa1 = *(const short8*)(Ab + 64*K);
  short8 pb0 = *(const short8*)(Wb);
  short8 pb1 = *(const short8*)(Wb + 64*K);
  *(short8*)&lds[0][0][lo]  = pa0;
  *(short8*)&lds[0][0][lo2] = pa1;
  *(short8*)&lds[0][1][lo]  = pb0;
  *(short8*)&lds[0][1][lo2] = pb1;

  f32x4 acc[4][4];
  f32x4 z = {0.f,0.f,0.f,0.f};
#pragma unroll
  for (int i = 0; i < 4; ++i)
#pragma unroll
    for (int j = 0; j < 4; ++j) acc[i][j] = z;

  for (int kt = 0; kt < NK; ++kt){
    __syncthreads();
    if (kt + 1 < NK){
      pa0 = *(const short8*)(Ab + (kt+1)*32);
      pa1 = *(const short8*)(Ab + (kt+1)*32 + 64*K);
      pb0 = *(const short8*)(Wb + (kt+1)*32);
      pb1 = *(const short8*)(Wb + (kt+1)*32 + 64*K);
    }
    const short* As = lds[kt & 1][0];
    const short* Bs = lds[kt & 1][1];
    short8 bfr[4];
#pragma unroll
    for (int nf = 0; nf < 4; ++nf)
      bfr[nf] = *(const short8*)&Bs[(wn*64 + nf*16 + (l & 15))*40 + (l >> 4)*8];
#pragma unroll
    for (int mf = 0; mf < 4; ++mf){
      short8 af = *(const short8*)&As[(wm*64 + mf*16 + (l & 15))*40 + (l >> 4)*8];
#pragma unroll
      for (int nf = 0; nf < 4; ++nf)
        acc[mf][nf] = __builtin_amdgcn_mfma_f32_16x16x32_bf16(af, bfr[nf], acc[mf][nf], 0, 0, 0);
    }
    if (kt + 1 < NK){
      int nb = (kt + 1) & 1;
      *(short8*)&lds[nb][0][lo]  = pa0;
      *(short8*)&lds[nb][0][lo2] = pa1;
      *(short8*)&lds[nb][1][lo]  = pb0;
      *(short8*)&lds[nb][1][lo2] = pb1;
    }
  }

  const int mrow0 = mt*128 + wm*64;
  const int ncol0 = nt*128 + wn*64;
#pragma unroll
  for (int nf = 0; nf < 4; ++nf){
    int n = ncol0 + nf*16 + (l & 15);      // n = g*1024 + jf*16 + jl
    int g  = n >> 10;
    int jfn = (n >> 4) & 63;
    int jl  = n & 15;
    float bs = bih[n] + bhh[n];
#pragma unroll
    for (int mf = 0; mf < 4; ++mf){
#pragma unroll
      for (int r = 0; r < 4; ++r){
        int m = mrow0 + mf*16 + (l >> 4)*4 + r;   // C/D: row=(l>>4)*4+r, col=l&15
        int b = m >> 9, t = m & 511;
        long idx = ((((long)t*8 + (b >> 4))*64 + jfn)*4 + g)*256 + (b & 15)*16 + jl;
        C[idx] = f2bf(acc[mf][nf][r] + bs);
      }
    }
  }
}

// ---------------- persistent LSTM scan (one launch per layer) ----------------
// grid (bt=8, jf=64) = 512 blocks x 256 thr; 2 blocks/CU. W register-pinned.
// RING=true : h slot per step (virgin addresses) -> producers store sc1
//   (write-through to MALL), consumers PLAIN cacheable dwordx4 loads (cannot
//   be stale: address never touched; XCD L2 fill shared by co-located blocks).
// RING=false: 2-slot ping-pong, R4-proven agent-scope relaxed atomics (MALL).
// Sync: stores -> vmcnt(0) -> __syncthreads -> 1 atomicAdd/block -> out/xg
//   (overlap) -> 1-lane/wave poll (counter==16) -> workgroup acquire fence.
// The barrier also closes the red[] cross-wave reuse race.
//
// h slot layout: region (bt,wv)=8KB; chunk c (16B) = h[bt*16 + (c&15)]
//   [wv*256 + (c>>6)*32 + ((c>>4)&3)*8 + e]. Consumer wave wv: a[ks] =
//   chunk[ks*64 + l]. Producer wave wv of block jf owns 8 full chunks.
template<int LAYER, bool RING>
__global__ __launch_bounds__(256, 2) void lstm_scan(
    short* __restrict__ hring, const short* __restrict__ Wsw, const short* __restrict__ xg,
    const float* __restrict__ om, const float* __restrict__ hm, const float* __restrict__ cm,
    short* __restrict__ out0, float* __restrict__ dout,
    int* __restrict__ cnt)       // [8 bt][512 t][4 quarter] counters, pre-zeroed
{
  const int tid = threadIdx.x;
  const int l = tid & 63, wv = tid >> 6;
  const int bt = blockIdx.x, jf = blockIdx.y;

  // ---- load W fragments once; pin in registers ----
  short8 w[4][8];
#pragma unroll
  for (int g = 0; g < 4; ++g){
    const short8* wp = (const short8*)Wsw + ((g*64 + jf)*32 + wv*8)*64 + l;
#pragma unroll
    for (int ks = 0; ks < 8; ++ks) w[g][ks] = wp[ks*64];
  }
  {
    f32x4* wf = (f32x4*)w;
#pragma unroll
    for (int i = 0; i < 32; ++i) asm volatile("" : "+v"(wf[i]));
  }

  // ---- elementwise-role constants ----
  const int bl = tid >> 4, jl = tid & 15;
  const int jcol = jf*16 + jl;
  const long bj = (long)(bt*16 + bl)*H_ + jcol;
  const float mo = om[bj], mh = hm[bj], mc = cm[bj];
  float c = 0.f;
  const int lsrc = ((bl >> 2) << 4) | jl;   // lane holding acc row bl, col jl
  const int rr = bl & 3;

  // consumer gather base (bytes within slot): region (bt,wv) + lane chunk
  const long cbyte = (long)(bt*4 + wv)*8192 + l*16;
  // producer: wave wv, lanes l<8 store chunk c = ((jf&15)>>1)*64
  //   + ((jf&1)*2 + (l>>2))*16 + wv*4 + (l&3) of region (bt, jf>>4)
  const long pbyte = (long)(bt*4 + (jf >> 4))*8192
                   + (long)((((jf >> 1) & 7))*64 + ((jf & 1)*2 + (l >> 2))*16 + wv*4 + (l & 3))*16;
  // sstage pack slot: wave region wv*64 shorts; chunk (jl>>3)*4 + (bl&3), elem jl&7
  const int sidx = wv*64 + ((jl >> 3)*4 + (bl & 3))*8 + (jl & 7);

  __shared__ float red[16*264];             // padded rows vs bank conflicts
  __shared__ __align__(16) short sstage[256];
  int* fl4 = cnt + (long)bt*T_*4;

  // xg prefetch for t=0
  const short* xg0 = xg + (((long)bt)*64 + jf)*1024;
  short xv0 = xg0[tid], xv1 = xg0[256 + tid], xv2 = xg0[512 + tid], xv3 = xg0[768 + tid];

  for (int t = 0; t < T_; ++t){
    const long slotoff  = RING ? (long)t*SLOT       : (long)(t & 1)*SLOT;
    const long nslotoff = RING ? (long)(t+1)*SLOT   : (long)((t+1) & 1)*SLOT;

    // ---- gather h slice ----
    const char* hsrc = (const char*)hring + slotoff + cbyte;
    short8 a[8];
    if constexpr (RING){
#pragma unroll
      for (int ks = 0; ks < 8; ++ks)
        a[ks] = *(const short8*)(hsrc + ks*1024);     // plain, cacheable, virgin
    } else {
#pragma unroll
      for (int ks = 0; ks < 8; ++ks){
        const u64* ap = (const u64*)(hsrc + ks*1024);
        union { u64 q[2]; short8 v; } uu;
        uu.q[0] = __hip_atomic_load(ap,     __ATOMIC_RELAXED, __HIP_MEMORY_SCOPE_AGENT);
        uu.q[1] = __hip_atomic_load(ap + 1, __ATOMIC_RELAXED, __HIP_MEMORY_SCOPE_AGENT);
        a[ks] = uu.v;
      }
    }

    f32x4 acc[4];
    f32x4 z = {0.f,0.f,0.f,0.f};
#pragma unroll
    for (int g = 0; g < 4; ++g) acc[g] = z;
#pragma unroll
    for (int g = 0; g < 4; ++g)
#pragma unroll
      for (int ks = 0; ks < 8; ++ks)
        acc[g] = __builtin_amdgcn_mfma_f32_16x16x32_bf16(a[ks], w[g][ks], acc[g], 0, 0, 0);

#pragma unroll
    for (int g = 0; g < 4; ++g)
#pragma unroll
      for (int r = 0; r < 4; ++r)
        red[(g*4 + r)*264 + tid] = acc[g][r];
    __syncthreads();

    // ---- elementwise (thread owns (bl, jl)) ----
    float gate[4];
    short xvv[4] = {xv0, xv1, xv2, xv3};
#pragma unroll
    for (int g = 0; g < 4; ++g){
      const float* rrow = &red[(g*4 + rr)*264];
      float s = rrow[lsrc] + rrow[64 + lsrc] + rrow[128 + lsrc] + rrow[192 + lsrc];
      gate[g] = s + bf2f(xvv[g]);
    }
    float ii = sigm(gate[0]);
    float ff = sigm(gate[1]);
    float gg = tanh_(gate[2]);
    float oo = sigm(gate[3]);
    float c2 = ff*c + ii*gg;
    float h2 = oo*tanh_(c2);
    c = c2*mc;
    float hn = h2*mh;

    if (t < T_ - 1){
      // ---- wave-local pack: each wave writes & reads ONLY its own 128B ----
      sstage[sidx] = f2bf(hn);
      asm volatile("s_waitcnt lgkmcnt(0)" ::: "memory");   // own wave's ds_write done
      __builtin_amdgcn_sched_barrier(0);
      if (l < 8){
        short8 pk = ((const short8*)sstage)[wv*8 + l];
        char* hdst = (char*)hring + nslotoff + pbyte;
        if constexpr (RING){
          asm volatile("global_store_dwordx4 %0, %1, off sc1" :: "v"(hdst), "v"(pk) : "memory");
        } else {
          union { short8 v; u64 q[2]; } uu; uu.v = pk;
          u64* qp = (u64*)hdst;
          __hip_atomic_store(qp,     uu.q[0], __ATOMIC_RELAXED, __HIP_MEMORY_SCOPE_AGENT);
          __hip_atomic_store(qp + 1, uu.q[1], __ATOMIC_RELAXED, __HIP_MEMORY_SCOPE_AGENT);
        }
      }
      asm volatile("s_waitcnt vmcnt(0)" ::: "memory");     // h at coherence point
      __syncthreads();                                     // all waves acked; red[] safe
      if (tid == 0)
        __hip_atomic_fetch_add(&fl4[t*4 + (jf >> 4)], 1, __ATOMIC_RELAXED, __HIP_MEMORY_SCOPE_AGENT);
    }

    // ---- out stores (plain; kernel-end release handles visibility) ----
    if (LAYER == 0){
      out0[((long)(bt*16 + bl)*T_ + t)*H_ + jcol] = f2bf(h2*mo);
    } else {
      dout[((long)(bt*16 + bl)*T_ + t)*H_ + jcol] = h2*mo;
      if (t == T_ - 1){
        dout[(long)B_*T_*H_ + bj] = hn;                    // hf
        dout[(long)B_*T_*H_ + (long)B_*H_ + bj] = c;       // cf
      }
    }

    if (t == T_ - 1) break;

    // ---- xg prefetch for t+1 (overlaps poll) ----
    const short* xgn = xg + (((long)(t+1)*8 + bt)*64 + jf)*1024;
    xv0 = xgn[tid]; xv1 = xgn[256 + tid]; xv2 = xgn[512 + tid]; xv3 = xgn[768 + tid];

    // ---- 1-lane-per-wave poll: quarter wv complete when counter == 16 ----
    if (l == 0){
      int g = 0;
      while (__hip_atomic_load(&fl4[t*4 + wv], __ATOMIC_RELAXED, __HIP_MEMORY_SCOPE_AGENT) != 16){
        if (++g > (1 << 20)) break;   // safety: wrong-answer instead of hang
      }
    }
    // compiler-only ordering: gather loads must not hoist above the poll.
    __builtin_amdgcn_fence(__ATOMIC_ACQUIRE, "workgroup");
  }
}

extern "C" void kernel_launch(void* const* d_in, const int* in_sizes, int n_in,
                              void* d_out, int out_size, void* d_ws, size_t ws_size,
                              hipStream_t stream){
  const float* x    = (const float*)d_in[0];
  const float* Wih0 = (const float*)d_in[1];
  const float* Whh0 = (const float*)d_in[2];
  const float* bih0 = (const float*)d_in[3];
  const float* bhh0 = (const float*)d_in[4];
  const float* Wih1 = (const float*)d_in[5];
  const float* Whh1 = (const float*)d_in[6];
  const float* bih1 = (const float*)d_in[7];
  const float* bhh1 = (const float*)d_in[8];
  const float* omsk = (const float*)d_in[9];
  const float* hmsk = (const float*)d_in[10];
  const float* cmsk = (const float*)d_in[11];
  float* out = (float*)d_out;

  char* p = (char*)d_ws;
  auto alloc = [&](size_t bytes)->char*{
    char* r = p; p += (bytes + 255) & ~(size_t)255; return r;
  };
  short* xg      = (short*)alloc((size_t)65536*4096*2);   // 512 MB swizzled xg (per-layer reuse)
  short* out0_bf = (short*)alloc((size_t)67108864*2);     // 128 MB layer-0 outputs
  short* x_bf    = (short*)out0_bf;                       // 64 MB alias (dead before out0 written)
  short* wih0_bf = (short*)alloc((size_t)2097152*2);
  short* wih1_bf = (short*)alloc((size_t)4194304*2);
  short* whh0_sw = (short*)alloc((size_t)4194304*2);
  short* whh1_sw = (short*)alloc((size_t)4194304*2);
  int*   cnt0    = (int*)alloc((size_t)8*512*4*4);        // 64 KB counters
  int*   cnt1    = (int*)alloc((size_t)8*512*4*4);
  // ring if it fits, else 2-slot ping-pong
  size_t fixed = (size_t)(p - (char*)d_ws);
  bool ring = (fixed + (size_t)512*SLOT) <= ws_size;
  short* hring = (short*)alloc(ring ? (size_t)512*SLOT : (size_t)2*SLOT);
  if ((size_t)(p - (char*)d_ws) > ws_size) return;   // cannot even fit fallback — bail

  // counters re-zeroed every call; h slot 0 = zeros (h_0 = 0)
  hipMemsetAsync(cnt0, 0, (size_t)8*512*4*4, stream);
  hipMemsetAsync(cnt1, 0, (size_t)8*512*4*4, stream);
  hipMemsetAsync(hring, 0, (size_t)SLOT, stream);

  // converts / weight swizzles
  cvt_bf16<<<33554432/4/256, 256, 0, stream>>>(x,    x_bf,    33554432/4);
  cvt_bf16<<<2097152/4/256,  256, 0, stream>>>(Wih0, wih0_bf, 2097152/4);
  cvt_bf16<<<4194304/4/256,  256, 0, stream>>>(Wih1, wih1_bf, 4194304/4);
  swz_whh <<<524288/256,     256, 0, stream>>>(Whh0, whh0_sw);
  swz_whh <<<524288/256,     256, 0, stream>>>(Whh1, whh1_sw);

  // ---- layer 0 ----
  proj_gemm<512><<<dim3(32, 512), 256, 0, stream>>>(x_bf, wih0_bf, bih0, bhh0, xg);
  if (ring)
    lstm_scan<0, true ><<<dim3(8, 64), 256, 0, stream>>>(hring, whh0_sw, xg,
        omsk, hmsk, cmsk, out0_bf, nullptr, cnt0);
  else
    lstm_scan<0, false><<<dim3(8, 64), 256, 0, stream>>>(hring, whh0_sw, xg,
        omsk, hmsk, cmsk, out0_bf, nullptr, cnt0);

  // ---- layer 1 ----
  proj_gemm<1024><<<dim3(32, 512), 256, 0, stream>>>(out0_bf, wih1_bf, bih1, bhh1, xg);
  if (ring)
    lstm_scan<1, true ><<<dim3(8, 64), 256, 0, stream>>>(hring, whh1_sw, xg,
        omsk + 131072, hmsk + 131072, cmsk + 131072, nullptr, out, cnt1);
  else
    lstm_scan<1, false><<<dim3(8, 64), 256, 0, stream>>>(hring, whh1_sw, xg,
        omsk + 131072, hmsk + 131072, cmsk + 131072, nullptr, out, cnt1);
}

// Round 8
// 4512.776 us; speedup vs baseline: 6.2828x; 1.6411x over previous
//
#include <hip/hip_runtime.h>

// Problem constants
#define B_  128
#define T_  512
#define I_  512
#define H_  1024
#define G4  4096   // 4*H
#define SLOT 262144L   // 256 KB per h ring slot (B*H*2)

typedef __attribute__((ext_vector_type(8))) short   short8;
typedef __attribute__((ext_vector_type(4))) short   short4v;
typedef __attribute__((ext_vector_type(4))) float   f32x4;
typedef unsigned long long u64;

__device__ __forceinline__ float bf2f(short u){
  return __uint_as_float(((unsigned)(unsigned short)u) << 16);
}
__device__ __forceinline__ short f2bf(float f){
  unsigned u = __float_as_uint(f);
  unsigned r = (u + 0x7FFFu + ((u >> 16) & 1u)) >> 16;  // RNE
  return (short)r;
}
__device__ __forceinline__ float sigm(float x){ return 1.0f/(1.0f + __expf(-x)); }
__device__ __forceinline__ float tanh_(float x){ return 1.0f - 2.0f/(__expf(2.0f*x) + 1.0f); }

// ---------------- fp32 -> bf16 elementwise convert (vectorized x4) ----------------
__global__ __launch_bounds__(256) void cvt_bf16(const float* __restrict__ in,
                                                short* __restrict__ out, int nq){
  int i = blockIdx.x*256 + threadIdx.x;
  if (i >= nq) return;
  float4 v = ((const float4*)in)[i];
  short4v o; o.x = f2bf(v.x); o.y = f2bf(v.y); o.z = f2bf(v.z); o.w = f2bf(v.w);
  ((short4v*)out)[i] = o;
}

// ---------------- W_hh fp32 [4096][1024] -> bf16 MFMA-fragment-swizzled ----------------
// NEW layout for 32-block scan: chunk idx c = ((jb*8 + wv)*32 + ks)*64 + l,
// wv = g*2 + ct, represents W[g*1024 + jb*32 + ct*16 + (l&15)][ks*32 + (l>>4)*8 + e]
__global__ __launch_bounds__(256) void swz_whh(const float* __restrict__ W,
                                               short* __restrict__ out){
  int c = blockIdx.x*256 + threadIdx.x;      // 0 .. 524287
  int l = c & 63, ks = (c >> 6) & 31, wvv = (c >> 11) & 7, jb = c >> 14;
  int g = wvv >> 1, ct = wvv & 1;
  long row = (long)(g*1024 + jb*32 + ct*16 + (l & 15));
  int col = ks*32 + (l >> 4)*8;
  const float* src = W + row*H_ + col;
  short8 o;
#pragma unroll
  for (int e = 0; e < 8; ++e) o[e] = f2bf(src[e]);
  ((short8*)out)[c] = o;
}

// ---------------- projection GEMM: C[m,n] = sum_k A[m,k]*W[n,k] + bih[n]+bhh[n] ----------------
// Output written in scan-swizzled xg layout:
//   idx = (((t*8 + bt)*32 + jb)*4 + g)*512 + bl*32 + jl5
template<int K>
__global__ __launch_bounds__(256) void proj_gemm(const short* __restrict__ A,
                                                 const short* __restrict__ W,
                                                 const float* __restrict__ bih,
                                                 const float* __restrict__ bhh,
                                                 short* __restrict__ C){
  __shared__ short lds[2][2][128*40];  // [buf][A/B][row*40+col], pad 40 kills conflicts
  const int tid = threadIdx.x;
  const int l  = tid & 63, wv = tid >> 6;
  const int wm = wv >> 1,  wn = wv & 1;
  const int nt = blockIdx.x, mt = blockIdx.y;
  const int r0 = tid >> 2, cb = (tid & 3) * 8;
  const short* Ab = A + (long)(mt*128 + r0)*K + cb;
  const short* Wb = W + (long)(nt*128 + r0)*K + cb;
  const int lo  = r0*40 + cb;
  const int lo2 = lo + 64*40;
  const int NK = K/32;

  short8 pa0 = *(const short8*)(Ab);
  short8 pa1 = *(const short8*)(Ab + 64*K);
  short8 pb0 = *(const short8*)(Wb);
  short8 pb1 = *(const short8*)(Wb + 64*K);
  *(short8*)&lds[0][0][lo]  = pa0;
  *(short8*)&lds[0][0][lo2] = pa1;
  *(short8*)&lds[0][1][lo]  = pb0;
  *(short8*)&lds[0][1][lo2] = pb1;

  f32x4 acc[4][4];
  f32x4 z = {0.f,0.f,0.f,0.f};
#pragma unroll
  for (int i = 0; i < 4; ++i)
#pragma unroll
    for (int j = 0; j < 4; ++j) acc[i][j] = z;

  for (int kt = 0; kt < NK; ++kt){
    __syncthreads();
    if (kt + 1 < NK){
      pa0 = *(const short8*)(Ab + (kt+1)*32);
      pa1 = *(const short8*)(Ab + (kt+1)*32 + 64*K);
      pb0 = *(const short8*)(Wb + (kt+1)*32);
      pb1 = *(const short8*)(Wb + (kt+1)*32 + 64*K);
    }
    const short* As = lds[kt & 1][0];
    const short* Bs = lds[kt & 1][1];
    short8 bfr[4];
#pragma unroll
    for (int nf = 0; nf < 4; ++nf)
      bfr[nf] = *(const short8*)&Bs[(wn*64 + nf*16 + (l & 15))*40 + (l >> 4)*8];
#pragma unroll
    for (int mf = 0; mf < 4; ++mf){
      short8 af = *(const short8*)&As[(wm*64 + mf*16 + (l & 15))*40 + (l >> 4)*8];
#pragma unroll
      for (int nf = 0; nf < 4; ++nf)
        acc[mf][nf] = __builtin_amdgcn_mfma_f32_16x16x32_bf16(af, bfr[nf], acc[mf][nf], 0, 0, 0);
    }
    if (kt + 1 < NK){
      int nb = (kt + 1) & 1;
      *(short8*)&lds[nb][0][lo]  = pa0;
      *(short8*)&lds[nb][0][lo2] = pa1;
      *(short8*)&lds[nb][1][lo]  = pb0;
      *(short8*)&lds[nb][1][lo2] = pb1;
    }
  }

  const int mrow0 = mt*128 + wm*64;
  const int ncol0 = nt*128 + wn*64;
#pragma unroll
  for (int nf = 0; nf < 4; ++nf){
    int n = ncol0 + nf*16 + (l & 15);      // n = g*1024 + jb*32 + jl5
    int g   = n >> 10;
    int jb  = (n & 1023) >> 5;
    int jl5 = n & 31;
    float bs = bih[n] + bhh[n];
#pragma unroll
    for (int mf = 0; mf < 4; ++mf){
#pragma unroll
      for (int r = 0; r < 4; ++r){
        int m = mrow0 + mf*16 + (l >> 4)*4 + r;   // C/D: row=(l>>4)*4+r, col=l&15
        int b = m >> 9, t = m & 511;
        long idx = ((((long)t*8 + (b >> 4))*32 + jb)*4 + g)*512 + (b & 15)*32 + jl5;
        C[idx] = f2bf(acc[mf][nf][r] + bs);
      }
    }
  }
}

// ---------------- persistent LSTM scan (one launch per layer) ----------------
// grid (bt=8, jb=32) = 256 blocks x 512 thr (8 waves); 1 block/CU guaranteed.
// Block (bt,jb) owns 32 j-cols x 4 gates. Wave wv = g*2+ct: gate g, col-tile ct,
// FULL K=1024 in-wave (32 MFMAs into 2 interleaved accs) -> NO K-reduce.
// W: 32 frags = 128 VGPR, register-pinned.
// Per step: stage group h (32KB) into LDS cooperatively (reg-staged, virgin ring
// addresses -> plain loads legal) -> barrier -> 32 MFMA/wave from ds_read_b128
// -> tiny acc exchange (4 floats/thread) -> EW -> sstage -> barrier ->
// wave0: pack 1KB region + sc1 stores + vmcnt + flag (agent store) ->
// out stores + xg prefetch (overlap) -> poll 32 flags (16 lanes x u64 agent
// loads, s_sleep backoff). G16-safe: all cross-block data via device-visible
// stores; flags/h virgin-per-call; replay-safe by determinism.
//
// h slot layout: chunk c (16B), c = bt*2048 + ks*64 + l holds
//   h[bt*16 + (l&15)][ks*32 + (l>>4)*8 + e]. Producer (bt,jb): ks=jb -> 64
//   contiguous chunks (1KB). Consumer stages all 2048 chunks of its bt.
template<int LAYER, bool RING>
__global__ __launch_bounds__(512, 2) void lstm_scan(
    short* __restrict__ hring, const short* __restrict__ Wsw, const short* __restrict__ xg,
    const float* __restrict__ om, const float* __restrict__ hm, const float* __restrict__ cm,
    short* __restrict__ out0, float* __restrict__ dout,
    int* __restrict__ flags)     // [8 bt][512 t][32 jb] ints, pre-zeroed
{
  const int tid = threadIdx.x;
  const int l = tid & 63, wv = tid >> 6;
  const int bt = blockIdx.x, jb = blockIdx.y;

  // ---- load W fragments once; pin in registers ----
  short8 w[32];
  {
    const short8* wp = (const short8*)Wsw + ((long)(jb*8 + wv)*32)*64 + l;
#pragma unroll
    for (int ks = 0; ks < 32; ++ks) w[ks] = wp[ks*64];
    f32x4* wf = (f32x4*)w;
#pragma unroll
    for (int i = 0; i < 32; ++i) asm volatile("" : "+v"(wf[i]));
  }

  // ---- elementwise-role constants (thread owns (bl, jl)) ----
  const int bl = tid >> 5, jl = tid & 31;
  const int jcol = jb*32 + jl;
  const long bj = (long)(bt*16 + bl)*H_ + jcol;
  const float mo = om[bj], mh = hm[bj], mc = cm[bj];
  float c = 0.f;
  // gate g read position: wave g*2+(jl>>4), lane (jl&15)+((bl>>2)<<4), reg bl&3
  const int rr = bl & 3;
  const int l2 = (jl & 15) + ((bl >> 2) << 4);
  // sstage slot: region chunk l' = bl + (jl>>3)*16, elem jl&7
  const int sidx = (bl + ((jl >> 3) << 4))*8 + (jl & 7);

  __shared__ __align__(16) short hbuf[2048*8];   // 32KB staged h
  __shared__ float red[8*264];                   // acc exchange, padded rows
  __shared__ __align__(16) short sstage[512];
  int* flbase = flags + (long)bt*T_*32;

  // xg prefetch for t=0
  const short* xg0 = xg + (((long)bt)*32 + jb)*2048;
  short xv0 = xg0[tid], xv1 = xg0[512 + tid], xv2 = xg0[1024 + tid], xv3 = xg0[1536 + tid];

  for (int t = 0; t < T_; ++t){
    const long slotoff  = RING ? (long)t*SLOT     : (long)(t & 1)*SLOT;
    const long nslotoff = RING ? (long)(t+1)*SLOT : (long)((t+1) & 1)*SLOT;

    // ---- stage h (group's 32KB) into LDS: each thread 4 chunks ----
    {
      const char* hsl = (const char*)hring + slotoff + (long)bt*32768;
#pragma unroll
      for (int i = 0; i < 4; ++i){
        int ci = wv*256 + i*64 + l;
        short8 v;
        if constexpr (RING){
          v = *(const short8*)(hsl + (long)ci*16);     // plain: virgin address
        } else {
          const u64* ap = (const u64*)(hsl + (long)ci*16);
          union { u64 q[2]; short8 s; } uu;
          uu.q[0] = __hip_atomic_load(ap,     __ATOMIC_RELAXED, __HIP_MEMORY_SCOPE_AGENT);
          uu.q[1] = __hip_atomic_load(ap + 1, __ATOMIC_RELAXED, __HIP_MEMORY_SCOPE_AGENT);
          v = uu.s;
        }
        *(short8*)&hbuf[ci*8] = v;
      }
    }
    __syncthreads();

    // ---- 32 MFMA, full K in-wave, 2 interleaved acc chains ----
    f32x4 acc0 = {0.f,0.f,0.f,0.f}, acc1 = {0.f,0.f,0.f,0.f};
#pragma unroll
    for (int kb = 0; kb < 4; ++kb){
      short8 aa[8];
#pragma unroll
      for (int k8 = 0; k8 < 8; ++k8)
        aa[k8] = *(const short8*)&hbuf[((kb*8 + k8)*64 + l)*8];
#pragma unroll
      for (int k8 = 0; k8 < 8; ++k8){
        if (k8 & 1) acc1 = __builtin_amdgcn_mfma_f32_16x16x32_bf16(aa[k8], w[kb*8 + k8], acc1, 0, 0, 0);
        else        acc0 = __builtin_amdgcn_mfma_f32_16x16x32_bf16(aa[k8], w[kb*8 + k8], acc0, 0, 0, 0);
      }
    }
    f32x4 accs;
#pragma unroll
    for (int r = 0; r < 4; ++r) accs[r] = acc0[r] + acc1[r];

    // ---- acc exchange (4 floats/thread) ----
    *(f32x4*)&red[wv*264 + l*4] = accs;
    __syncthreads();

    // ---- elementwise ----
    float gate[4];
    short xvv[4] = {xv0, xv1, xv2, xv3};
#pragma unroll
    for (int g = 0; g < 4; ++g){
      int wvg = g*2 + (jl >> 4);
      gate[g] = red[wvg*264 + l2*4 + rr] + bf2f(xvv[g]);
    }
    float ii = sigm(gate[0]);
    float ff = sigm(gate[1]);
    float gg = tanh_(gate[2]);
    float oo = sigm(gate[3]);
    float c2 = ff*c + ii*gg;
    float h2 = oo*tanh_(c2);
    c = c2*mc;
    float hn = h2*mh;

    if (t == T_ - 1){
      if (LAYER == 0){
        out0[((long)(bt*16 + bl)*T_ + t)*H_ + jcol] = f2bf(h2*mo);
      } else {
        dout[((long)(bt*16 + bl)*T_ + t)*H_ + jcol] = h2*mo;
        dout[(long)B_*T_*H_ + bj] = hn;                    // hf
        dout[(long)B_*T_*H_ + (long)B_*H_ + bj] = c;       // cf
      }
      break;
    }

    // ---- stage h_next, publish (wave 0 only; race-free via barrier) ----
    sstage[sidx] = f2bf(hn);
    __syncthreads();

    if (wv == 0){
      short8 pk = ((const short8*)sstage)[l];
      char* hdst = (char*)hring + nslotoff + ((long)bt*2048 + jb*64 + l)*16;
      if constexpr (RING){
        asm volatile("global_store_dwordx4 %0, %1, off sc1" :: "v"(hdst), "v"(pk) : "memory");
      } else {
        union { short8 s; u64 q[2]; } uu; uu.s = pk;
        u64* qp = (u64*)hdst;
        __hip_atomic_store(qp,     uu.q[0], __ATOMIC_RELAXED, __HIP_MEMORY_SCOPE_AGENT);
        __hip_atomic_store(qp + 1, uu.q[1], __ATOMIC_RELAXED, __HIP_MEMORY_SCOPE_AGENT);
      }
      asm volatile("s_waitcnt vmcnt(0)" ::: "memory");     // h at coherence point
      if (tid == 0)
        __hip_atomic_store(&flbase[(long)t*32 + jb], 1, __ATOMIC_RELAXED, __HIP_MEMORY_SCOPE_AGENT);
    }

    // ---- out stores + xg prefetch (overlap the poll) ----
    if (LAYER == 0){
      out0[((long)(bt*16 + bl)*T_ + t)*H_ + jcol] = f2bf(h2*mo);
    } else {
      dout[((long)(bt*16 + bl)*T_ + t)*H_ + jcol] = h2*mo;
    }
    const short* xgn = xg + (((long)(t+1)*8 + bt)*32 + jb)*2048;
    xv0 = xgn[tid]; xv1 = xgn[512 + tid]; xv2 = xgn[1024 + tid]; xv3 = xgn[1536 + tid];

    // ---- poll all 32 producer flags: 16 lanes x u64 agent loads ----
    {
      const u64* fp = (const u64*)&flbase[(long)t*32];
      int spins = 0;
      while (true){
        int ok = 1;
        if (l < 16){
          u64 v = __hip_atomic_load(fp + l, __ATOMIC_RELAXED, __HIP_MEMORY_SCOPE_AGENT);
          ok = ((unsigned)v != 0u) & ((unsigned)(v >> 32) != 0u);
        }
        if (__all(ok)) break;
        if (++spins > (1 << 18)) break;   // safety: wrong-answer instead of hang
        if (spins > 4) __builtin_amdgcn_s_sleep(1);
      }
    }
    __builtin_amdgcn_fence(__ATOMIC_ACQUIRE, "workgroup");  // compiler ordering only
  }
}

extern "C" void kernel_launch(void* const* d_in, const int* in_sizes, int n_in,
                              void* d_out, int out_size, void* d_ws, size_t ws_size,
                              hipStream_t stream){
  const float* x    = (const float*)d_in[0];
  const float* Wih0 = (const float*)d_in[1];
  const float* Whh0 = (const float*)d_in[2];
  const float* bih0 = (const float*)d_in[3];
  const float* bhh0 = (const float*)d_in[4];
  const float* Wih1 = (const float*)d_in[5];
  const float* Whh1 = (const float*)d_in[6];
  const float* bih1 = (const float*)d_in[7];
  const float* bhh1 = (const float*)d_in[8];
  const float* omsk = (const float*)d_in[9];
  const float* hmsk = (const float*)d_in[10];
  const float* cmsk = (const float*)d_in[11];
  float* out = (float*)d_out;

  char* p = (char*)d_ws;
  auto alloc = [&](size_t bytes)->char*{
    char* r = p; p += (bytes + 255) & ~(size_t)255; return r;
  };
  short* xg      = (short*)alloc((size_t)65536*4096*2);   // 512 MB swizzled xg (per-layer reuse)
  short* out0_bf = (short*)alloc((size_t)67108864*2);     // 128 MB layer-0 outputs
  short* x_bf    = (short*)out0_bf;                       // 64 MB alias (dead before out0 written)
  short* wih0_bf = (short*)alloc((size_t)2097152*2);
  short* wih1_bf = (short*)alloc((size_t)4194304*2);
  short* whh0_sw = (short*)alloc((size_t)4194304*2);
  short* whh1_sw = (short*)alloc((size_t)4194304*2);
  int*   flags0  = (int*)alloc((size_t)8*512*32*4);       // 512 KB flags
  int*   flags1  = (int*)alloc((size_t)8*512*32*4);
  // ring if it fits, else 2-slot ping-pong
  size_t fixed = (size_t)(p - (char*)d_ws);
  bool ring = (fixed + (size_t)512*SLOT) <= ws_size;
  short* hring = (short*)alloc(ring ? (size_t)512*SLOT : (size_t)2*SLOT);
  if ((size_t)(p - (char*)d_ws) > ws_size) return;   // cannot even fit fallback — bail

  // flags re-zeroed every call; h slot 0 = zeros (h_0 = 0)
  hipMemsetAsync(flags0, 0, (size_t)8*512*32*4, stream);
  hipMemsetAsync(flags1, 0, (size_t)8*512*32*4, stream);
  hipMemsetAsync(hring, 0, (size_t)SLOT, stream);

  // converts / weight swizzles
  cvt_bf16<<<33554432/4/256, 256, 0, stream>>>(x,    x_bf,    33554432/4);
  cvt_bf16<<<2097152/4/256,  256, 0, stream>>>(Wih0, wih0_bf, 2097152/4);
  cvt_bf16<<<4194304/4/256,  256, 0, stream>>>(Wih1, wih1_bf, 4194304/4);
  swz_whh <<<524288/256,     256, 0, stream>>>(Whh0, whh0_sw);
  swz_whh <<<524288/256,     256, 0, stream>>>(Whh1, whh1_sw);

  // ---- layer 0 ----
  proj_gemm<512><<<dim3(32, 512), 256, 0, stream>>>(x_bf, wih0_bf, bih0, bhh0, xg);
  if (ring)
    lstm_scan<0, true ><<<dim3(8, 32), 512, 0, stream>>>(hring, whh0_sw, xg,
        omsk, hmsk, cmsk, out0_bf, nullptr, flags0);
  else
    lstm_scan<0, false><<<dim3(8, 32), 512, 0, stream>>>(hring, whh0_sw, xg,
        omsk, hmsk, cmsk, out0_bf, nullptr, flags0);

  // ---- layer 1 ----
  proj_gemm<1024><<<dim3(32, 512), 256, 0, stream>>>(out0_bf, wih1_bf, bih1, bhh1, xg);
  if (ring)
    lstm_scan<1, true ><<<dim3(8, 32), 512, 0, stream>>>(hring, whh1_sw, xg,
        omsk + 131072, hmsk + 131072, cmsk + 131072, nullptr, out, flags1);
  else
    lstm_scan<1, false><<<dim3(8, 32), 512, 0, stream>>>(hring, whh1_sw, xg,
        omsk + 131072, hmsk + 131072, cmsk + 131072, nullptr, out, flags1);
}